// Round 5
// baseline (8108.670 us; speedup 1.0000x reference)
//
#include <hip/hip_runtime.h>

#define Bv    64
#define Sv    200
#define DKv   32
#define NQ1v  4097
#define NWG   8      // workgroups (blocks) per batch element
#define TPB   256    // threads per workgroup
#define ROWS  2      // rows per thread per b: 8*256*2 = 4096, +1 special
#define NSTEP 199

typedef unsigned long long u64;

template<int I> struct ic { static constexpr int value = I; };

__device__ __forceinline__ float fsig(float x) {
  return __builtin_amdgcn_rcpf(1.0f + __builtin_amdgcn_exp2f(x * -1.4426950408889634f));
}
__device__ __forceinline__ float ftanh_(float x) {
  return fmaf(2.0f, fsig(2.0f * x), -1.0f);
}
__device__ __forceinline__ u64 packvt(float v, unsigned tag) {
  return ((u64)tag << 32) | (u64)__float_as_uint(v);
}
__device__ __forceinline__ u64 fresh_read(u64* p) {
  return __hip_atomic_fetch_add(p, 0ull, __ATOMIC_RELAXED, __HIP_MEMORY_SCOPE_AGENT);
}
__device__ __forceinline__ void fresh_write(u64* p, u64 v) {
  (void)__hip_atomic_exchange(p, v, __ATOMIC_RELAXED, __HIP_MEMORY_SCOPE_AGENT);
}

__global__ void lpkt_init(float* out) {
  int i = threadIdx.x;
  if (i < Bv) out[i * Sv] = 0.0f;
}

// Two batch elements per block (b, b+32): while one b waits on its cross-WG
// sync, the block computes the other b's bulk+chain — hides post->poll RTT.
__global__ __launch_bounds__(TPB, 2) void lpkt_main(
    const int* __restrict__ e_data, const int* __restrict__ at_data,
    const int* __restrict__ it_data, const float* __restrict__ a_data,
    const float* __restrict__ q_matrix,
    const float* __restrict__ E_e, const float* __restrict__ E_at, const float* __restrict__ E_it,
    const float* __restrict__ W1, const float* __restrict__ b1,
    const float* __restrict__ W2, const float* __restrict__ b2,
    const float* __restrict__ W3, const float* __restrict__ b3,
    const float* __restrict__ W4, const float* __restrict__ b4,
    const float* __restrict__ W5, const float* __restrict__ b5,
    const float* __restrict__ h0, float* __restrict__ out,
    u64* __restrict__ partial)
{
  const int tid  = threadIdx.x;
  const int wg   = blockIdx.x & (NWG - 1);
  const int pair = blockIdx.x / NWG;       // 0..31
  const int bA   = pair;
  const int bB   = pair + 32;
  const int k    = tid & 31;
  const int p    = tid >> 5;               // 0..7
  const int nbase = wg * (TPB * ROWS);

  __shared__ float W23T[128 * 64];               // [j][2k]=W2[k][j], [2k+1]=W3[k][j]
  __shared__ __align__(16) float W1L[32 * 100];
  __shared__ __align__(16) float W4L[32 * 100];
  __shared__ __align__(16) float W5L[32 * 68];
  __shared__ float bL[5 * 32];
  __shared__ __align__(16) float xw_lds[2][96];
  __shared__ __align__(16) float it_lds[2][DKv];
  __shared__ __align__(16) float lcA[2][DKv], lcB[2][DKv];
  __shared__ __align__(16) float ht_lds[2][DKv];
  __shared__ __align__(16) float LG_lds[2][DKv];
  __shared__ __align__(16) float c_lds[2][DKv];
  __shared__ __align__(16) float red[8][DKv];
  __shared__ __align__(16) float red2[8][DKv];
  __shared__ float ht_part[2][DKv];
  __shared__ __align__(16) float h49[2][DKv];

  // ---- one-time weight staging
  for (int idx = tid; idx < 128 * 32; idx += TPB) {
    int j = idx & 127, kk = idx >> 7;
    W23T[j * 64 + 2 * kk]     = W2[kk * 128 + j];
    W23T[j * 64 + 2 * kk + 1] = W3[kk * 128 + j];
  }
  for (int idx = tid; idx < 32 * 96; idx += TPB) {
    int r = idx / 96, c = idx % 96;
    W1L[r * 100 + c] = W1[idx];
    W4L[r * 100 + c] = W4[idx];
  }
  for (int idx = tid; idx < 32 * 64; idx += TPB) {
    int r = idx >> 6, c = idx & 63;
    W5L[r * 68 + c] = W5[idx];
  }
  if (tid < 32) {
    bL[0 * 32 + tid] = b1[tid]; bL[1 * 32 + tid] = b2[tid];
    bL[2 * 32 + tid] = b3[tid]; bL[3 * 32 + tid] = b4[tid];
    bL[4 * 32 + tid] = b5[tid];
  }
  if (tid < DKv) {
    ht_part[0][tid] = 0.0f; ht_part[1][tid] = 0.0f;
    lcB[0][tid] = 0.0f;     lcB[1][tid] = 0.0f;     // lp = 0 at t=0
  }
  if (wg == 0 && tid < DKv) {
    float v = h0[4096 * DKv + tid];
    h49[0][tid] = v; h49[1][tid] = v;
  }

  // ---- persistent register state for both b's (h0 is shared across batch)
  float h[2][ROWS][DKv];
#pragma unroll
  for (int r = 0; r < ROWS; r++) {
    const float4* hp = (const float4*)(h0 + (size_t)(nbase + r * TPB + tid) * DKv);
#pragma unroll
    for (int i = 0; i < 8; i++) {
      float4 v = hp[i];
      h[0][r][4*i] = v.x; h[0][r][4*i+1] = v.y; h[0][r][4*i+2] = v.z; h[0][r][4*i+3] = v.w;
      h[1][r][4*i] = v.x; h[1][r][4*i+1] = v.y; h[1][r][4*i+2] = v.z; h[1][r][4*i+3] = v.w;
    }
  }
  const float* q0A = q_matrix + (size_t)e_data[bA * Sv] * NQ1v;
  const float* q0B = q_matrix + (size_t)e_data[bB * Sv] * NQ1v;
  float qc[2][ROWS];
  float qc49[2] = {0.0f, 0.0f};
#pragma unroll
  for (int r = 0; r < ROWS; r++) {
    qc[0][r] = q0A[nbase + r * TPB + tid];
    qc[1][r] = q0B[nbase + r * TPB + tid];
  }
  if (wg == 0 && tid < DKv) { qc49[0] = q0A[4096]; qc49[1] = q0B[4096]; }
  __syncthreads();

  // ---- phase 0: h_tilde0 for both b's; post tag=1
#pragma unroll
  for (int bi = 0; bi < 2; bi++) {
#pragma unroll
    for (int r = 0; r < ROWS; r++) {
      if (qc[bi][r] != 0.0f) {
#pragma unroll
        for (int kk = 0; kk < DKv; kk++) atomicAdd(&ht_part[bi][kk], h[bi][r][kk]);
      }
    }
    if (wg == 0 && tid < DKv && qc49[bi] != 0.0f) atomicAdd(&ht_part[bi][tid], h49[bi][tid]);
  }
  __syncthreads();
  if (tid < DKv) {
    fresh_write(&partial[((size_t)(1 % 3) * Bv + bA) * (NWG * DKv) + wg * DKv + tid],
                packvt(ht_part[0][tid], 1u));
    fresh_write(&partial[((size_t)(1 % 3) * Bv + bB) * (NWG * DKv) + wg * DKv + tid],
                packvt(ht_part[1][tid], 1u));
  }

  float acc[ROWS][DKv];   // bulk accumulator, reused by each b's chain
  float qn[2][ROWS];
  float qn49[2];

  // =================== time loop ===================
  for (int t = 0; t < NSTEP; t++) {
    const unsigned tau_g = (unsigned)(t + 1);
    const unsigned tau_p = (unsigned)(t + 2);

    // ---- A: loads + LDS staging for BOTH b's (consumed late; latency hidden)
    {
      const int ecA = e_data[bA * Sv + t], enA = e_data[bA * Sv + t + 1];
      const int atA = at_data[bA * Sv + t], itA = it_data[bA * Sv + t];
      const float avA = a_data[bA * Sv + t];
      const int ecB = e_data[bB * Sv + t], enB = e_data[bB * Sv + t + 1];
      const int atB = at_data[bB * Sv + t], itB = it_data[bB * Sv + t];
      const float avB = a_data[bB * Sv + t];
      const float* qnA = q_matrix + (size_t)enA * NQ1v;
      const float* qnB = q_matrix + (size_t)enB * NQ1v;
#pragma unroll
      for (int r = 0; r < ROWS; r++) {
        qn[0][r] = qnA[nbase + r * TPB + tid];
        qn[1][r] = qnB[nbase + r * TPB + tid];
      }
      qn49[0] = qn49[1] = 0.0f;
      if (wg == 0 && tid < DKv) { qn49[0] = qnA[4096]; qn49[1] = qnB[4096]; }

      if (tid < 96)
        xw_lds[0][tid] = (tid < 32) ? E_e[(size_t)ecA * DKv + tid]
                       : (tid < 64) ? E_at[(size_t)atA * DKv + (tid - 32)] : avA;
      else if (tid < 128)
        it_lds[0][tid - 96] = E_it[(size_t)itA * DKv + (tid - 96)];
      else if (tid < 224) {
        int u = tid - 128;
        xw_lds[1][u] = (u < 32) ? E_e[(size_t)ecB * DKv + u]
                     : (u < 64) ? E_at[(size_t)atB * DKv + (u - 32)] : avB;
      } else
        it_lds[1][tid - 224] = E_it[(size_t)itB * DKv + (tid - 224)];
    }

    // ---- chain for one b: bulk -> sync -> small-net -> h update -> post
    auto chain = [&](auto BIC) {
      constexpr int BI = decltype(BIC)::value;
      const int bX = BI ? bB : bA;
      float* lc_cur  = (t & 1) ? &lcB[BI][0] : &lcA[BI][0];
      float* lc_prev = (t & 1) ? &lcA[BI][0] : &lcB[BI][0];

      // bulk matvec W4h . h[BI] (uniform W4 -> s_load)
#pragma unroll
      for (int kk = 0; kk < DKv; kk++) {
        float a0 = 0.0f, a1 = 0.0f;
#pragma unroll
        for (int d = 0; d < DKv; d += 4) {
          float4 w = *(const float4*)&W4[kk * 96 + d];
          a0 = fmaf(w.x, h[BI][0][d+0], a0); a1 = fmaf(w.x, h[BI][1][d+0], a1);
          a0 = fmaf(w.y, h[BI][0][d+1], a0); a1 = fmaf(w.y, h[BI][1][d+1], a1);
          a0 = fmaf(w.z, h[BI][0][d+2], a0); a1 = fmaf(w.z, h[BI][1][d+2], a1);
          a0 = fmaf(w.w, h[BI][0][d+3], a0); a1 = fmaf(w.w, h[BI][1][d+3], a1);
        }
        acc[0][kk] = a0; acc[1][kk] = a1;
      }
      __syncthreads();   // X1

      // S1: w0 poll+gather | w1 lc matvec
      if (tid < DKv) {
        u64* pb = partial + ((size_t)(tau_g % 3) * Bv + bX) * (NWG * DKv) + tid;
        u64 v[NWG];
        for (;;) {
          bool ok = true;
#pragma unroll
          for (int w2 = 0; w2 < NWG; w2++) {
            v[w2] = fresh_read(&pb[w2 * DKv]);
            ok = ok && ((unsigned)(v[w2] >> 32) == tau_g);
          }
          if (ok) break;
          __builtin_amdgcn_s_sleep(2);
        }
        float s = 0.0f;
#pragma unroll
        for (int w2 = 0; w2 < NWG; w2++) s += __uint_as_float((unsigned)v[w2]);
        ht_lds[BI][tid] = s;
      } else if (tid >= 64 && tid < 96) {
        const int kx = tid - 64;
        float s = bL[0 * 32 + kx];
        const float4* wp = (const float4*)&W1L[kx * 100];
        const float4* xp = (const float4*)&xw_lds[BI][0];
#pragma unroll
        for (int i = 0; i < 24; i++) {
          float4 w = wp[i]; float4 x = xp[i];
          s = fmaf(x.x, w.x, s); s = fmaf(x.y, w.y, s);
          s = fmaf(x.z, w.z, s); s = fmaf(x.w, w.w, s);
        }
        lc_cur[kx] = s;
      }
      __syncthreads();   // X2

      // D: lg/gl split-8
      {
        const int seg = p >> 1;
        const float* sp = (seg == 0) ? lc_prev : (seg == 1) ? &it_lds[BI][0]
                        : (seg == 2) ? lc_cur  : &ht_lds[BI][0];
        const int off = (p & 1) * 16;
        float xv[16];
#pragma unroll
        for (int i = 0; i < 4; i++) {
          float4 v = ((const float4*)(sp + off))[i];
          xv[4*i] = v.x; xv[4*i+1] = v.y; xv[4*i+2] = v.z; xv[4*i+3] = v.w;
        }
        float s2 = 0.0f, s3 = 0.0f;
        const int jb = 16 * p;
#pragma unroll
        for (int i = 0; i < 16; i++) {
          float2 w = *(const float2*)&W23T[(jb + i) * 64 + 2 * k];
          s2 = fmaf(xv[i], w.x, s2);
          s3 = fmaf(xv[i], w.y, s3);
        }
        red[p][k] = s2; red2[p][k] = s3;
      }
      __syncthreads();   // X3

      // E: LG | zero ht_part[BI]
      if (tid < DKv) {
        float s2 = bL[1 * 32 + tid], s3 = bL[2 * 32 + tid];
#pragma unroll
        for (int pp = 0; pp < 8; pp++) { s2 += red[pp][tid]; s3 += red2[pp][tid]; }
        LG_lds[BI][tid] = fsig(s3) * (ftanh_(s2) + 1.0f) * 0.5f;
      } else if (tid >= 128 && tid < 160) ht_part[BI][tid - 128] = 0.0f;
      __syncthreads();   // X4

      // F: c split-8 | y partials (wg0, t>=1)
      {
        const float* up = (p < 4) ? &LG_lds[BI][8 * p] : &it_lds[BI][8 * (p - 4)];
        const float4* wp = (const float4*)&W4L[k * 100 + 32 + 8 * p];
        float4 w0 = wp[0], w1 = wp[1];
        float pc = 0.0f;
        pc = fmaf(up[0], w0.x, pc); pc = fmaf(up[1], w0.y, pc);
        pc = fmaf(up[2], w0.z, pc); pc = fmaf(up[3], w0.w, pc);
        pc = fmaf(up[4], w1.x, pc); pc = fmaf(up[5], w1.y, pc);
        pc = fmaf(up[6], w1.z, pc); pc = fmaf(up[7], w1.w, pc);
        red[p][k] = pc;
      }
      if (wg == 0 && t >= 1 && tid >= 64 && tid < 128) {
        const int p2 = p - 2;
        const float* zs = (p2 == 0) ? &xw_lds[BI][0] : &ht_lds[BI][0];
        const float4* wp = (const float4*)&W5L[k * 68 + 32 * p2];
        float acc5 = 0.0f;
#pragma unroll
        for (int i = 0; i < 8; i++) {
          float4 w = wp[i]; float4 z = ((const float4*)zs)[i];
          acc5 = fmaf(z.x, w.x, acc5); acc5 = fmaf(z.y, w.y, acc5);
          acc5 = fmaf(z.z, w.z, acc5); acc5 = fmaf(z.w, w.w, acc5);
        }
        red2[p2][k] = acc5;
      }
      __syncthreads();   // X5

      // G: c sum | y finish
      if (tid < DKv) {
        float s = bL[3 * 32 + tid];
#pragma unroll
        for (int pp = 0; pp < 8; pp++) s += red[pp][tid];
        c_lds[BI][tid] = s;
      } else if (wg == 0 && t >= 1 && tid >= 96 && tid < 128) {
        const int kx = tid - 96;
        float s = fsig(bL[4 * 32 + kx] + red2[0][kx] + red2[1][kx]);
#pragma unroll
        for (int m = 1; m < 32; m <<= 1) s += __shfl_xor(s, m);
        if (tid == 96) out[bX * Sv + t] = s * (1.0f / DKv);
      }
      __syncthreads();   // X6

      // H: h[BI] update + sparse h_tilde contributions
#pragma unroll
      for (int r = 0; r < ROWS; r++) {
        const float qcr = qc[BI][r];
#pragma unroll
        for (int kq = 0; kq < 8; kq++) {
          float4 cv = ((const float4*)&c_lds[BI][0])[kq];
          float4 gv = ((const float4*)&LG_lds[BI][0])[kq];
          float g0 = fsig(acc[r][4*kq+0] + cv.x);
          float g1 = fsig(acc[r][4*kq+1] + cv.y);
          float g2 = fsig(acc[r][4*kq+2] + cv.z);
          float g3 = fsig(acc[r][4*kq+3] + cv.w);
          h[BI][r][4*kq+0] = fmaf(g0, h[BI][r][4*kq+0], qcr * gv.x);
          h[BI][r][4*kq+1] = fmaf(g1, h[BI][r][4*kq+1], qcr * gv.y);
          h[BI][r][4*kq+2] = fmaf(g2, h[BI][r][4*kq+2], qcr * gv.z);
          h[BI][r][4*kq+3] = fmaf(g3, h[BI][r][4*kq+3], qcr * gv.w);
        }
        if (qn[BI][r] != 0.0f) {
#pragma unroll
          for (int kk = 0; kk < DKv; kk++) atomicAdd(&ht_part[BI][kk], h[BI][r][kk]);
        }
        qc[BI][r] = qn[BI][r];
      }
      if (wg == 0 && tid < DKv) {   // special row 4096
        float hh[DKv];
#pragma unroll
        for (int i = 0; i < 8; i++) {
          float4 v = ((const float4*)&h49[BI][0])[i];
          hh[4*i] = v.x; hh[4*i+1] = v.y; hh[4*i+2] = v.z; hh[4*i+3] = v.w;
        }
        float a = c_lds[BI][tid];
#pragma unroll
        for (int d = 0; d < DKv; d += 4) {
          float4 w = *(const float4*)&W4L[tid * 100 + d];
          a = fmaf(w.x, hh[d+0], a); a = fmaf(w.y, hh[d+1], a);
          a = fmaf(w.z, hh[d+2], a); a = fmaf(w.w, hh[d+3], a);
        }
        float hn = fmaf(fsig(a), h49[BI][tid], qc49[BI] * LG_lds[BI][tid]);
        h49[BI][tid] = hn;
        if (qn49[BI] != 0.0f) atomicAdd(&ht_part[BI][tid], hn);
        qc49[BI] = qn49[BI];
      }
      __syncthreads();   // X7

      // I: post tagged partial
      if (tid < DKv)
        fresh_write(&partial[((size_t)(tau_p % 3) * Bv + bX) * (NWG * DKv) + wg * DKv + tid],
                    packvt(ht_part[BI][tid], tau_p));
    };

    chain(ic<0>{});   // b0: its sync RTT was covered by b1's work last iteration
    chain(ic<1>{});   // b1: covered by bulk0 + chain0 above
  }

  // =================== epilogue: y for pred index 199 (wg0 blocks) ===================
  if (wg == 0) {
    const unsigned tau_f = (unsigned)(NSTEP + 1);   // 200
    const int bi = (tid >= 128) ? 1 : 0;
    const int lane = tid & 127;
    const int bX = bi ? bB : bA;
    if (lane < DKv) {
      u64* pb = partial + ((size_t)(tau_f % 3) * Bv + bX) * (NWG * DKv) + lane;
      u64 v[NWG];
      for (;;) {
        bool ok = true;
#pragma unroll
        for (int w2 = 0; w2 < NWG; w2++) {
          v[w2] = fresh_read(&pb[w2 * DKv]);
          ok = ok && ((unsigned)(v[w2] >> 32) == tau_f);
        }
        if (ok) break;
        __builtin_amdgcn_s_sleep(2);
      }
      float s = 0.0f;
#pragma unroll
      for (int w2 = 0; w2 < NWG; w2++) s += __uint_as_float((unsigned)v[w2]);
      ht_lds[bi][lane] = s;
      xw_lds[bi][lane] = E_e[(size_t)e_data[bX * Sv + 199] * DKv + lane];
    }
    __syncthreads();
    if (lane >= 64) {
      const int p2 = ((lane >> 5) & 3) - 2;
      if (p2 >= 0 && lane < 128) {
        const float* zs = (p2 == 0) ? &xw_lds[bi][0] : &ht_lds[bi][0];
        const float4* wp = (const float4*)&W5L[k * 68 + 32 * p2];
        float acc5 = 0.0f;
#pragma unroll
        for (int i = 0; i < 8; i++) {
          float4 w = wp[i]; float4 z = ((const float4*)zs)[i];
          acc5 = fmaf(z.x, w.x, acc5); acc5 = fmaf(z.y, w.y, acc5);
          acc5 = fmaf(z.z, w.z, acc5); acc5 = fmaf(z.w, w.w, acc5);
        }
        red2[bi * 2 + p2][k] = acc5;
      }
    }
    __syncthreads();
    if (lane >= 96 && lane < 128) {
      const int kx = lane - 96;
      float s = fsig(bL[4 * 32 + kx] + red2[bi * 2 + 0][kx] + red2[bi * 2 + 1][kx]);
#pragma unroll
      for (int m = 1; m < 32; m <<= 1) s += __shfl_xor(s, m);
      if (kx == 0) out[bX * Sv + 199] = s * (1.0f / DKv);
    }
  }
}

extern "C" void kernel_launch(void* const* d_in, const int* in_sizes, int n_in,
                              void* d_out, int out_size, void* d_ws, size_t ws_size,
                              hipStream_t stream) {
  const int*   e_data   = (const int*)d_in[0];
  const int*   at_data  = (const int*)d_in[1];
  const int*   it_data  = (const int*)d_in[2];
  const float* a_data   = (const float*)d_in[3];
  const float* q_matrix = (const float*)d_in[4];
  const float* E_e      = (const float*)d_in[5];
  const float* E_at     = (const float*)d_in[6];
  const float* E_it     = (const float*)d_in[7];
  const float* W1 = (const float*)d_in[8];
  const float* b1 = (const float*)d_in[9];
  const float* W2 = (const float*)d_in[10];
  const float* b2 = (const float*)d_in[11];
  const float* W3 = (const float*)d_in[12];
  const float* b3 = (const float*)d_in[13];
  const float* W4 = (const float*)d_in[14];
  const float* b4 = (const float*)d_in[15];
  const float* W5 = (const float*)d_in[16];
  const float* b5 = (const float*)d_in[17];
  const float* h0 = (const float*)d_in[18];
  float* out = (float*)d_out;

  u64* partial = (u64*)d_ws;   // [3][Bv][NWG][DKv] tagged (tag<<32|value) words

  lpkt_init<<<1, 64, 0, stream>>>(out);
  lpkt_main<<<dim3((Bv / 2) * NWG), dim3(TPB), 0, stream>>>(
      e_data, at_data, it_data, a_data, q_matrix, E_e, E_at, E_it,
      W1, b1, W2, b2, W3, b3, W4, b4, W5, b5, h0, out, partial);
}

// Round 7
// 6396.557 us; speedup vs baseline: 1.2677x; 1.2677x over previous
//
#include <hip/hip_runtime.h>

#define Bv    64
#define Sv    200
#define DKv   32
#define NQ1v  4097
#define NWG   8      // workgroups per batch element
#define TPB   512    // 8 waves; 1 row per thread
#define NSTEP 199

typedef unsigned long long u64;

__device__ __forceinline__ float fsig(float x) {
  return __builtin_amdgcn_rcpf(1.0f + __builtin_amdgcn_exp2f(x * -1.4426950408889634f));
}
__device__ __forceinline__ float ftanh_(float x) {
  return fmaf(2.0f, fsig(2.0f * x), -1.0f);
}
__device__ __forceinline__ u64 packvt(float v, unsigned tag) {
  return ((u64)tag << 32) | (u64)__float_as_uint(v);
}
__device__ __forceinline__ u64 fresh_read(u64* p) {
  return __hip_atomic_fetch_add(p, 0ull, __ATOMIC_RELAXED, __HIP_MEMORY_SCOPE_AGENT);
}
__device__ __forceinline__ void fresh_write(u64* p, u64 v) {
  (void)__hip_atomic_exchange(p, v, __ATOMIC_RELAXED, __HIP_MEMORY_SCOPE_AGENT);
}

__global__ void lpkt_init(float* out) {
  int i = threadIdx.x;
  if (i < Bv) out[i * Sv] = 0.0f;
}

// blockIdx = wg*64 + b  =>  XCD (blockIdx%8) = b%8: all 8 partner WGs of one
// batch element share an XCD -> post/poll atomics stay in one L2.
// Every LDS producer->consumer crosses a __syncthreads; cross-lane data inside
// a segment moves only via __shfl (registers) or wave-uniform s_loads.
__global__ __launch_bounds__(TPB, 4) void lpkt_main(
    const int* __restrict__ e_data, const int* __restrict__ at_data,
    const int* __restrict__ it_data, const float* __restrict__ a_data,
    const float* __restrict__ q_matrix,
    const float* __restrict__ E_e, const float* __restrict__ E_at, const float* __restrict__ E_it,
    const float* __restrict__ W1, const float* __restrict__ b1,
    const float* __restrict__ W2, const float* __restrict__ b2,
    const float* __restrict__ W3, const float* __restrict__ b3,
    const float* __restrict__ W4, const float* __restrict__ b4,
    const float* __restrict__ W5, const float* __restrict__ b5,
    const float* __restrict__ h0, float* __restrict__ out,
    u64* __restrict__ partial)
{
  const int tid  = threadIdx.x;
  const int b    = blockIdx.x & 63;
  const int wg   = blockIdx.x >> 6;
  const int lane = tid & 63;
  const int wave = tid >> 6;
  const int row  = wg * TPB + tid;       // 0..4095

  // transposed, +1-padded weights: lane j reads [i*33+j] conflict-free
  __shared__ float W2T[128 * 33], W3T[128 * 33];
  __shared__ float W1T[96 * 33];
  __shared__ float W4cT[64 * 33];        // W4cT[d][j] = W4[j][32+d]
  __shared__ float W4hT[32 * 33];        // W4hT[d][j] = W4[j][d]
  __shared__ float W5T[64 * 33];
  __shared__ float bs[5 * 32];
  __shared__ __align__(16) float lc_s[2][DKv];
  __shared__ __align__(16) float ht_s[DKv];
  __shared__ __align__(16) float LG_s[DKv], c_s[DKv];
  __shared__ __align__(16) float ht_part[2][DKv];
  __shared__ __align__(16) float h49[DKv];

  // ---- one-time weight staging
  for (int idx = tid; idx < 128 * 32; idx += TPB) {
    int i = idx & 127, j = idx >> 7;
    W2T[i * 33 + j] = W2[j * 128 + i];
    W3T[i * 33 + j] = W3[j * 128 + i];
  }
  for (int idx = tid; idx < 32 * 96; idx += TPB) {
    int j = idx / 96, d = idx % 96;
    W1T[d * 33 + j] = W1[idx];
    float v = W4[idx];
    if (d < 32) W4hT[d * 33 + j] = v;
    else        W4cT[(d - 32) * 33 + j] = v;
  }
  for (int idx = tid; idx < 32 * 64; idx += TPB) {
    int j = idx >> 6, i = idx & 63;
    W5T[i * 33 + j] = W5[idx];
  }
  if (tid < 32) {
    bs[tid] = b1[tid]; bs[32 + tid] = b2[tid]; bs[64 + tid] = b3[tid];
    bs[96 + tid] = b4[tid]; bs[128 + tid] = b5[tid];
    ht_part[0][tid] = 0.0f; ht_part[1][tid] = 0.0f;
    lc_s[0][tid] = 0.0f; lc_s[1][tid] = 0.0f;        // lp = 0 at t=0
  }
  if (wg == 0 && tid < DKv) h49[tid] = h0[4096 * DKv + tid];

  // ---- persistent row state (1 row/thread)
  float h[DKv];
  {
    const float4* hp = (const float4*)(h0 + (size_t)row * DKv);
#pragma unroll
    for (int i = 0; i < 8; i++) {
      float4 v = hp[i];
      h[4*i] = v.x; h[4*i+1] = v.y; h[4*i+2] = v.z; h[4*i+3] = v.w;
    }
  }
  float qc = q_matrix[(size_t)e_data[b * Sv] * NQ1v + row];
  float qc49 = 0.0f;
  if (wg == 0 && wave == 0 && lane < DKv)
    qc49 = q_matrix[(size_t)e_data[b * Sv] * NQ1v + 4096];
  __syncthreads();

  // ---- phase 0: h_tilde0 into buf[1]; post tag=1
  if (qc != 0.0f) {
#pragma unroll
    for (int kk = 0; kk < DKv; kk++) atomicAdd(&ht_part[1][kk], h[kk]);
  }
  if (wg == 0 && wave == 0 && lane < DKv && qc49 != 0.0f)
    atomicAdd(&ht_part[1][lane], h49[lane]);
  __syncthreads();
  if (wave == 0 && lane < DKv) {
    fresh_write(&partial[((size_t)(1 % 3) * Bv + b) * (NWG * DKv) + wg * DKv + lane],
                packvt(ht_part[1][lane], 1u));
    ht_part[1][lane] = 0.0f;   // next write: H(t=1), after B1(1)
  }

  // =================== time loop (3 barriers/step) ===================
  for (int t = 0; t < NSTEP; t++) {
    const int par = t & 1;
    const unsigned tau_g = (unsigned)(t + 1);
    const unsigned tau_p = (unsigned)(t + 2);

    // wave-uniform scalars for this step
    const int ec  = e_data[b * Sv + t];
    const int atc = at_data[b * Sv + t];
    const int itc = it_data[b * Sv + t];
    const float av = a_data[b * Sv + t];
    const float* eerow = E_e  + (size_t)ec  * DKv;   // uniform rows -> s_loads
    const float* atrow = E_at + (size_t)atc * DKv;
    const float* itrow = E_it + (size_t)itc * DKv;

    // prefetch next q entry
    const float* qnr = q_matrix + (size_t)e_data[b * Sv + t + 1] * NQ1v;
    float qn = qnr[row];
    float qn49 = 0.0f;
    if (wg == 0 && wave == 0 && lane < DKv) qn49 = qnr[4096];

    // ---- bulk matvec: acc = W4h . h (uniform W4 -> s_load)
    float acc[DKv];
#pragma unroll
    for (int kk = 0; kk < DKv; kk++) {
      float a = 0.0f;
#pragma unroll
      for (int d = 0; d < DKv; d += 4) {
        float4 w = *(const float4*)&W4[kk * 96 + d];
        a = fmaf(w.x, h[d+0], a); a = fmaf(w.y, h[d+1], a);
        a = fmaf(w.z, h[d+2], a); a = fmaf(w.w, h[d+3], a);
      }
      acc[kk] = a;
    }

    // ---- SEG1 (wave0): poll->ht_s (lanes<32) | lc->lc_s (lanes>=32)
    if (wave == 0) {
      if (lane < 32) {
        u64* pb = partial + ((size_t)(tau_g % 3) * Bv + b) * (NWG * DKv) + lane;
        u64 v[NWG];
        for (;;) {
          bool ok = true;
#pragma unroll
          for (int w2 = 0; w2 < NWG; w2++) {
            v[w2] = fresh_read(&pb[w2 * DKv]);
            ok = ok && ((unsigned)(v[w2] >> 32) == tau_g);
          }
          if (ok) break;
          __builtin_amdgcn_s_sleep(2);
        }
        float s = 0.0f;
#pragma unroll
        for (int w2 = 0; w2 < NWG; w2++) s += __uint_as_float((unsigned)v[w2]);
        ht_s[lane] = s;
      } else {
        const int jx = lane - 32;
        float s = bs[jx];
#pragma unroll
        for (int i = 0; i < 32; i++) s = fmaf(eerow[i], W1T[i * 33 + jx], s);
#pragma unroll
        for (int i = 0; i < 32; i++) s = fmaf(atrow[i], W1T[(32 + i) * 33 + jx], s);
#pragma unroll
        for (int i = 0; i < 32; i++) s = fmaf(av,       W1T[(64 + i) * 33 + jx], s);
        lc_s[par][jx] = s;
      }
    }
    __syncthreads();   // B0: ht_s, lc_s[par] published

    // ---- SEG2 (wave0): lg/gl -> LG (regs+LDS), c via shfl, y
    float LGreg = 0.0f, creg = 0.0f;
    if (wave == 0) {
      const int jx = lane & 31;
      float s = (lane < 32) ? bs[32 + jx] : bs[64 + jx];
      const float* WT = (lane < 32) ? W2T : W3T;
#pragma unroll
      for (int i = 0; i < 32; i++) s = fmaf(lc_s[1 - par][i], WT[i * 33 + jx], s);
#pragma unroll
      for (int i = 0; i < 32; i++) s = fmaf(itrow[i],         WT[(32 + i) * 33 + jx], s);
#pragma unroll
      for (int i = 0; i < 32; i++) s = fmaf(lc_s[par][i],     WT[(64 + i) * 33 + jx], s);
#pragma unroll
      for (int i = 0; i < 32; i++) s = fmaf(ht_s[i],          WT[(96 + i) * 33 + jx], s);
      float v = (lane < 32) ? ftanh_(s) : fsig(s);
      float pr = __shfl_xor(v, 32);
      // all 64 lanes hold LG_{jx}: lo half v=lg, pr=gl; hi half v=gl, pr=lg
      LGreg = (lane < 32) ? pr * (v + 1.0f) * 0.5f : v * (pr + 1.0f) * 0.5f;
      if (lane < 32) {
        LG_s[lane] = LGreg;
        float c = bs[96 + lane];
#pragma unroll
        for (int d = 0; d < 32; d++)
          c = fmaf(__shfl(LGreg, d), W4cT[d * 33 + lane], c);   // reg broadcast
#pragma unroll
        for (int d = 0; d < 32; d++)
          c = fmaf(itrow[d], W4cT[(32 + d) * 33 + lane], c);
        creg = c; c_s[lane] = c;
      } else if (wg == 0 && t >= 1) {
        float y = bs[128 + jx];
#pragma unroll
        for (int i = 0; i < 32; i++) y = fmaf(eerow[i], W5T[i * 33 + jx], y);
#pragma unroll
        for (int i = 0; i < 32; i++) y = fmaf(ht_s[i],  W5T[(32 + i) * 33 + jx], y);
        y = fsig(y);
#pragma unroll
        for (int m = 1; m < 32; m <<= 1) y += __shfl_xor(y, m);
        if (lane == 32) out[b * Sv + t] = y * (1.0f / DKv);
      }
    }
    __syncthreads();   // B1: LG_s, c_s published

    // ---- SEG3 (all): row update + sparse h_tilde atomics
#pragma unroll
    for (int kk = 0; kk < DKv; kk++) {
      float g = fsig(acc[kk] + c_s[kk]);
      h[kk] = fmaf(g, h[kk], qc * LG_s[kk]);
    }
    if (qn != 0.0f) {
#pragma unroll
      for (int kk = 0; kk < DKv; kk++) atomicAdd(&ht_part[par][kk], h[kk]);
    }
    qc = qn;
    if (wg == 0 && wave == 0 && lane < DKv) {   // special row 4096 (regs for LG/c)
      float a = creg;
#pragma unroll
      for (int d = 0; d < DKv; d++) a = fmaf(W4hT[d * 33 + lane], h49[d], a);
      float hold = h49[lane];
      float hn = fmaf(fsig(a), hold, qc49 * LGreg);
      h49[lane] = hn;
      if (qn49 != 0.0f) atomicAdd(&ht_part[par][lane], hn);
      qc49 = qn49;
    }
    __syncthreads();   // B2: ht_part[par] complete (incl. special)

    // ---- post + zero (wave0); other waves race into t+1 bulk
    if (wave == 0 && lane < DKv) {
      fresh_write(&partial[((size_t)(tau_p % 3) * Bv + b) * (NWG * DKv) + wg * DKv + lane],
                  packvt(ht_part[par][lane], tau_p));
      ht_part[par][lane] = 0.0f;   // next write guarded by B1(t+2)
    }
  }

  // =================== epilogue: out[199] ===================
  if (wg == 0 && wave == 0 && lane < 32) {
    const unsigned tau_f = (unsigned)(NSTEP + 1);   // 200
    u64* pb = partial + ((size_t)(tau_f % 3) * Bv + b) * (NWG * DKv) + lane;
    u64 v[NWG];
    for (;;) {
      bool ok = true;
#pragma unroll
      for (int w2 = 0; w2 < NWG; w2++) {
        v[w2] = fresh_read(&pb[w2 * DKv]);
        ok = ok && ((unsigned)(v[w2] >> 32) == tau_f);
      }
      if (ok) break;
      __builtin_amdgcn_s_sleep(2);
    }
    float s = 0.0f;
#pragma unroll
    for (int w2 = 0; w2 < NWG; w2++) s += __uint_as_float((unsigned)v[w2]);
    ht_s[lane] = s;
  }
  __syncthreads();   // publish ht_s for the y lanes
  if (wg == 0 && wave == 0 && lane >= 32) {
    const int jx = lane - 32;
    const float* enrow = E_e + (size_t)e_data[b * Sv + NSTEP] * DKv;
    float y = bs[128 + jx];
#pragma unroll
    for (int i = 0; i < 32; i++) y = fmaf(enrow[i], W5T[i * 33 + jx], y);
#pragma unroll
    for (int i = 0; i < 32; i++) y = fmaf(ht_s[i],  W5T[(32 + i) * 33 + jx], y);
    y = fsig(y);
#pragma unroll
    for (int m = 1; m < 32; m <<= 1) y += __shfl_xor(y, m);
    if (lane == 32) out[b * Sv + NSTEP] = y * (1.0f / DKv);
  }
}

extern "C" void kernel_launch(void* const* d_in, const int* in_sizes, int n_in,
                              void* d_out, int out_size, void* d_ws, size_t ws_size,
                              hipStream_t stream) {
  const int*   e_data   = (const int*)d_in[0];
  const int*   at_data  = (const int*)d_in[1];
  const int*   it_data  = (const int*)d_in[2];
  const float* a_data   = (const float*)d_in[3];
  const float* q_matrix = (const float*)d_in[4];
  const float* E_e      = (const float*)d_in[5];
  const float* E_at     = (const float*)d_in[6];
  const float* E_it     = (const float*)d_in[7];
  const float* W1 = (const float*)d_in[8];
  const float* b1 = (const float*)d_in[9];
  const float* W2 = (const float*)d_in[10];
  const float* b2 = (const float*)d_in[11];
  const float* W3 = (const float*)d_in[12];
  const float* b3 = (const float*)d_in[13];
  const float* W4 = (const float*)d_in[14];
  const float* b4 = (const float*)d_in[15];
  const float* W5 = (const float*)d_in[16];
  const float* b5 = (const float*)d_in[17];
  const float* h0 = (const float*)d_in[18];
  float* out = (float*)d_out;

  u64* partial = (u64*)d_ws;   // [3][Bv][NWG][DKv] tagged (tag<<32|value) words

  lpkt_init<<<1, 64, 0, stream>>>(out);
  lpkt_main<<<dim3(Bv * NWG), dim3(TPB), 0, stream>>>(
      e_data, at_data, it_data, a_data, q_matrix, E_e, E_at, E_it,
      W1, b1, W2, b2, W3, b3, W4, b4, W5, b5, h0, out, partial);
}

// Round 10
// 5401.471 us; speedup vs baseline: 1.5012x; 1.1842x over previous
//
#include <hip/hip_runtime.h>

#define Bv    64
#define Sv    200
#define DKv   32
#define NQ1v  4097
#define NWG   4      // workgroups per batch element
#define TPB   1024   // 16 waves; 1 row per thread
#define NSTEP 199

typedef unsigned long long u64;

__device__ __forceinline__ float fsig(float x) {
  return __builtin_amdgcn_rcpf(1.0f + __builtin_amdgcn_exp2f(x * -1.4426950408889634f));
}
__device__ __forceinline__ float ftanh_(float x) {
  return fmaf(2.0f, fsig(2.0f * x), -1.0f);
}
__device__ __forceinline__ u64 packvt(float v, unsigned tag) {
  return ((u64)tag << 32) | (u64)__float_as_uint(v);
}
__device__ __forceinline__ u64 fresh_read(u64* p) {
  return __hip_atomic_fetch_add(p, 0ull, __ATOMIC_RELAXED, __HIP_MEMORY_SCOPE_AGENT);
}
__device__ __forceinline__ void fresh_write(u64* p, u64 v) {
  (void)__hip_atomic_exchange(p, v, __ATOMIC_RELAXED, __HIP_MEMORY_SCOPE_AGENT);
}

__global__ void lpkt_init(float* out) {
  int i = threadIdx.x;
  if (i < Bv) out[i * Sv] = 0.0f;
}

// Grid = 256 blocks of 1024 threads = exactly 1 block/CU (VGPR=128 forced by
// 1024-thread blocks makes 2/CU impossible) -> co-residency guaranteed with
// slack; no exact-fit scheduling cliff (suspected R8/R9 hang cause).
// blockIdx = wg*64 + b  =>  XCD (blockIdx%8) = b%8: all 4 partner WGs of one
// batch element share an XCD -> post/poll atomics stay in one L2.
__global__ __launch_bounds__(TPB, 1) void lpkt_main(
    const int* __restrict__ e_data, const int* __restrict__ at_data,
    const int* __restrict__ it_data, const float* __restrict__ a_data,
    const float* __restrict__ q_matrix,
    const float* __restrict__ E_e, const float* __restrict__ E_at, const float* __restrict__ E_it,
    const float* __restrict__ W1, const float* __restrict__ b1,
    const float* __restrict__ W2, const float* __restrict__ b2,
    const float* __restrict__ W3, const float* __restrict__ b3,
    const float* __restrict__ W4, const float* __restrict__ b4,
    const float* __restrict__ W5, const float* __restrict__ b5,
    const float* __restrict__ h0, float* __restrict__ out,
    u64* __restrict__ partial)
{
  const int tid  = threadIdx.x;
  const int b    = blockIdx.x & 63;
  const int wg   = blockIdx.x >> 6;      // 0..3
  const int lane = tid & 63;
  const int wave = tid >> 6;             // 0..15
  const int row  = wg * TPB + tid;       // 0..4095

  // transposed, +1-padded weights: lane j reads [i*33+j] conflict-free
  __shared__ float W2T[128 * 33], W3T[128 * 33];
  __shared__ float W1T[96 * 33];
  __shared__ float W4cT[64 * 33];        // W4cT[d][j] = W4[j][32+d]
  __shared__ float W4hT[32 * 33];        // W4hT[d][j] = W4[j][d]
  __shared__ float W5T[64 * 33];
  __shared__ float bs[5 * 32];
  __shared__ __align__(16) float lc_s[2][DKv];
  __shared__ __align__(16) float ht_s[DKv];
  __shared__ __align__(16) float LG_s[DKv], c_s[DKv];
  __shared__ __align__(16) float ht_part[2][DKv];
  __shared__ __align__(16) float h49[DKv];

  // ---- one-time weight staging
  for (int idx = tid; idx < 128 * 32; idx += TPB) {
    int i = idx & 127, j = idx >> 7;
    W2T[i * 33 + j] = W2[j * 128 + i];
    W3T[i * 33 + j] = W3[j * 128 + i];
  }
  for (int idx = tid; idx < 32 * 96; idx += TPB) {
    int j = idx / 96, d = idx % 96;
    W1T[d * 33 + j] = W1[idx];
    float v = W4[idx];
    if (d < 32) W4hT[d * 33 + j] = v;
    else        W4cT[(d - 32) * 33 + j] = v;
  }
  for (int idx = tid; idx < 32 * 64; idx += TPB) {
    int j = idx >> 6, i = idx & 63;
    W5T[i * 33 + j] = W5[idx];
  }
  if (tid < 32) {
    bs[tid] = b1[tid]; bs[32 + tid] = b2[tid]; bs[64 + tid] = b3[tid];
    bs[96 + tid] = b4[tid]; bs[128 + tid] = b5[tid];
    ht_part[0][tid] = 0.0f; ht_part[1][tid] = 0.0f;
    lc_s[0][tid] = 0.0f; lc_s[1][tid] = 0.0f;        // lp = 0 at t=0
  }
  if (wg == 0 && tid < DKv) h49[tid] = h0[4096 * DKv + tid];

  // ---- persistent row state (1 row/thread)
  float h[DKv];
  {
    const float4* hp = (const float4*)(h0 + (size_t)row * DKv);
#pragma unroll
    for (int i = 0; i < 8; i++) {
      float4 v = hp[i];
      h[4*i] = v.x; h[4*i+1] = v.y; h[4*i+2] = v.z; h[4*i+3] = v.w;
    }
  }
  float qc = q_matrix[(size_t)e_data[b * Sv] * NQ1v + row];
  float qc49 = 0.0f;
  if (wg == 0 && wave == 0 && lane < DKv)
    qc49 = q_matrix[(size_t)e_data[b * Sv] * NQ1v + 4096];
  __syncthreads();

  // ---- phase 0: h_tilde0 into buf[1]; post tag=1
  if (qc != 0.0f) {
#pragma unroll
    for (int kk = 0; kk < DKv; kk++) atomicAdd(&ht_part[1][kk], h[kk]);
  }
  if (wg == 0 && wave == 0 && lane < DKv && qc49 != 0.0f)
    atomicAdd(&ht_part[1][lane], h49[lane]);
  __syncthreads();
  if (wave == 0 && lane < DKv) {
    fresh_write(&partial[((size_t)(1 % 3) * Bv + b) * (NWG * DKv) + wg * DKv + lane],
                packvt(ht_part[1][lane], 1u));
    ht_part[1][lane] = 0.0f;   // next write: SEG3(t=1), after B1(1)
  }

  // =================== time loop (3 barriers/step) ===================
  for (int t = 0; t < NSTEP; t++) {
    const int par = t & 1;
    const unsigned tau_g = (unsigned)(t + 1);
    const unsigned tau_p = (unsigned)(t + 2);

    // wave-uniform scalars for this step
    const int ec  = e_data[b * Sv + t];
    const int atc = at_data[b * Sv + t];
    const int itc = it_data[b * Sv + t];
    const float av = a_data[b * Sv + t];
    const float* eerow = E_e  + (size_t)ec  * DKv;   // uniform rows -> s_loads
    const float* atrow = E_at + (size_t)atc * DKv;
    const float* itrow = E_it + (size_t)itc * DKv;

    // prefetch next q entry
    const float* qnr = q_matrix + (size_t)e_data[b * Sv + t + 1] * NQ1v;
    float qn = qnr[row];
    float qn49 = 0.0f;
    if (wg == 0 && wave == 0 && lane < DKv) qn49 = qnr[4096];

    // ---- bulk matvec: acc = W4h . h (uniform W4 -> s_load)
    float acc[DKv];
#pragma unroll
    for (int kk = 0; kk < DKv; kk++) {
      float a = 0.0f;
#pragma unroll
      for (int d = 0; d < DKv; d += 4) {
        float4 w = *(const float4*)&W4[kk * 96 + d];
        a = fmaf(w.x, h[d+0], a); a = fmaf(w.y, h[d+1], a);
        a = fmaf(w.z, h[d+2], a); a = fmaf(w.w, h[d+3], a);
      }
      acc[kk] = a;
    }

    // ---- SEG1 (wave0): poll->ht_s (lanes<32) | lc->lc_s (lanes>=32)
    if (wave == 0) {
      if (lane < 32) {
        u64* pb = partial + ((size_t)(tau_g % 3) * Bv + b) * (NWG * DKv) + lane;
        u64 v[NWG];
        for (;;) {
          bool ok = true;
#pragma unroll
          for (int w2 = 0; w2 < NWG; w2++) {
            v[w2] = fresh_read(&pb[w2 * DKv]);
            ok = ok && ((unsigned)(v[w2] >> 32) == tau_g);
          }
          if (ok) break;
          __builtin_amdgcn_s_sleep(2);
        }
        float s = 0.0f;
#pragma unroll
        for (int w2 = 0; w2 < NWG; w2++) s += __uint_as_float((unsigned)v[w2]);
        ht_s[lane] = s;
      } else {
        const int jx = lane - 32;
        float s = bs[jx];
#pragma unroll
        for (int i = 0; i < 32; i++) s = fmaf(eerow[i], W1T[i * 33 + jx], s);
#pragma unroll
        for (int i = 0; i < 32; i++) s = fmaf(atrow[i], W1T[(32 + i) * 33 + jx], s);
#pragma unroll
        for (int i = 0; i < 32; i++) s = fmaf(av,       W1T[(64 + i) * 33 + jx], s);
        lc_s[par][jx] = s;
      }
    }
    __syncthreads();   // B0: ht_s, lc_s[par] published

    // ---- SEG2: wave0: lg/gl -> LG, c | wave1 (wg0): y output for step t
    float LGreg = 0.0f, creg = 0.0f;
    if (wave == 0) {
      const int jx = lane & 31;
      float s = (lane < 32) ? bs[32 + jx] : bs[64 + jx];
      const float* WT = (lane < 32) ? W2T : W3T;
#pragma unroll
      for (int i = 0; i < 32; i++) s = fmaf(lc_s[1 - par][i], WT[i * 33 + jx], s);
#pragma unroll
      for (int i = 0; i < 32; i++) s = fmaf(itrow[i],         WT[(32 + i) * 33 + jx], s);
#pragma unroll
      for (int i = 0; i < 32; i++) s = fmaf(lc_s[par][i],     WT[(64 + i) * 33 + jx], s);
#pragma unroll
      for (int i = 0; i < 32; i++) s = fmaf(ht_s[i],          WT[(96 + i) * 33 + jx], s);
      float v = (lane < 32) ? ftanh_(s) : fsig(s);
      float pr = __shfl_xor(v, 32);
      // all 64 lanes hold LG_{jx}: lo half v=lg, pr=gl; hi half v=gl, pr=lg
      LGreg = (lane < 32) ? pr * (v + 1.0f) * 0.5f : v * (pr + 1.0f) * 0.5f;
      if (lane < 32) {
        LG_s[lane] = LGreg;
        float c = bs[96 + lane];
#pragma unroll
        for (int d = 0; d < 32; d++)
          c = fmaf(__shfl(LGreg, d), W4cT[d * 33 + lane], c);   // reg broadcast
#pragma unroll
        for (int d = 0; d < 32; d++)
          c = fmaf(itrow[d], W4cT[(32 + d) * 33 + lane], c);
        creg = c; c_s[lane] = c;
      }
    } else if (wg == 0 && wave == 1 && t >= 1 && lane < 32) {
      // y for out[t]: needs ht_s (valid post-B0) + eerow; off wave0's path
      float y = bs[128 + lane];
#pragma unroll
      for (int i = 0; i < 32; i++) y = fmaf(eerow[i], W5T[i * 33 + lane], y);
#pragma unroll
      for (int i = 0; i < 32; i++) y = fmaf(ht_s[i],  W5T[(32 + i) * 33 + lane], y);
      y = fsig(y);
#pragma unroll
      for (int m = 1; m < 32; m <<= 1) y += __shfl_xor(y, m);
      if (lane == 0) out[b * Sv + t] = y * (1.0f / DKv);
    }
    __syncthreads();   // B1: LG_s, c_s published

    // ---- SEG3 (all): row update + sparse h_tilde atomics
#pragma unroll
    for (int kk = 0; kk < DKv; kk++) {
      float g = fsig(acc[kk] + c_s[kk]);
      h[kk] = fmaf(g, h[kk], qc * LG_s[kk]);
    }
    if (qn != 0.0f) {
#pragma unroll
      for (int kk = 0; kk < DKv; kk++) atomicAdd(&ht_part[par][kk], h[kk]);
    }
    qc = qn;
    if (wg == 0 && wave == 0 && lane < DKv) {   // special row 4096 (regs for LG/c)
      float a = creg;
#pragma unroll
      for (int d = 0; d < DKv; d++) a = fmaf(W4hT[d * 33 + lane], h49[d], a);
      float hold = h49[lane];
      float hn = fmaf(fsig(a), hold, qc49 * LGreg);
      h49[lane] = hn;
      if (qn49 != 0.0f) atomicAdd(&ht_part[par][lane], hn);
      qc49 = qn49;
    }
    __syncthreads();   // B2: ht_part[par] complete (incl. special)

    // ---- post + zero (wave0); other waves race into t+1 bulk
    if (wave == 0 && lane < DKv) {
      fresh_write(&partial[((size_t)(tau_p % 3) * Bv + b) * (NWG * DKv) + wg * DKv + lane],
                  packvt(ht_part[par][lane], tau_p));
      ht_part[par][lane] = 0.0f;   // next write guarded by B1(t+2)
    }
  }

  // =================== epilogue: out[199] ===================
  if (wg == 0 && wave == 0 && lane < 32) {
    const unsigned tau_f = (unsigned)(NSTEP + 1);   // 200
    u64* pb = partial + ((size_t)(tau_f % 3) * Bv + b) * (NWG * DKv) + lane;
    u64 v[NWG];
    for (;;) {
      bool ok = true;
#pragma unroll
      for (int w2 = 0; w2 < NWG; w2++) {
        v[w2] = fresh_read(&pb[w2 * DKv]);
        ok = ok && ((unsigned)(v[w2] >> 32) == tau_f);
      }
      if (ok) break;
      __builtin_amdgcn_s_sleep(2);
    }
    float s = 0.0f;
#pragma unroll
    for (int w2 = 0; w2 < NWG; w2++) s += __uint_as_float((unsigned)v[w2]);
    ht_s[lane] = s;
  }
  __syncthreads();   // publish ht_s for the y lanes
  if (wg == 0 && wave == 0 && lane >= 32) {
    const int jx = lane - 32;
    const float* enrow = E_e + (size_t)e_data[b * Sv + NSTEP] * DKv;
    float y = bs[128 + jx];
#pragma unroll
    for (int i = 0; i < 32; i++) y = fmaf(enrow[i], W5T[i * 33 + jx], y);
#pragma unroll
    for (int i = 0; i < 32; i++) y = fmaf(ht_s[i],  W5T[(32 + i) * 33 + jx], y);
    y = fsig(y);
#pragma unroll
    for (int m = 1; m < 32; m <<= 1) y += __shfl_xor(y, m);
    if (lane == 32) out[b * Sv + NSTEP] = y * (1.0f / DKv);
  }
}

extern "C" void kernel_launch(void* const* d_in, const int* in_sizes, int n_in,
                              void* d_out, int out_size, void* d_ws, size_t ws_size,
                              hipStream_t stream) {
  const int*   e_data   = (const int*)d_in[0];
  const int*   at_data  = (const int*)d_in[1];
  const int*   it_data  = (const int*)d_in[2];
  const float* a_data   = (const float*)d_in[3];
  const float* q_matrix = (const float*)d_in[4];
  const float* E_e      = (const float*)d_in[5];
  const float* E_at     = (const float*)d_in[6];
  const float* E_it     = (const float*)d_in[7];
  const float* W1 = (const float*)d_in[8];
  const float* b1 = (const float*)d_in[9];
  const float* W2 = (const float*)d_in[10];
  const float* b2 = (const float*)d_in[11];
  const float* W3 = (const float*)d_in[12];
  const float* b3 = (const float*)d_in[13];
  const float* W4 = (const float*)d_in[14];
  const float* b4 = (const float*)d_in[15];
  const float* W5 = (const float*)d_in[16];
  const float* b5 = (const float*)d_in[17];
  const float* h0 = (const float*)d_in[18];
  float* out = (float*)d_out;

  u64* partial = (u64*)d_ws;   // [3][Bv][NWG][DKv] tagged (tag<<32|value) words

  lpkt_init<<<1, 64, 0, stream>>>(out);
  lpkt_main<<<dim3(Bv * NWG), dim3(TPB), 0, stream>>>(
      e_data, at_data, it_data, a_data, q_matrix, E_e, E_at, E_it,
      W1, b1, W2, b2, W3, b3, W4, b4, W5, b5, h0, out, partial);
}

// Round 11
// 5313.816 us; speedup vs baseline: 1.5260x; 1.0165x over previous
//
#include <hip/hip_runtime.h>

#define Bv    64
#define Sv    200
#define DKv   32
#define NQ1v  4097
#define NWG   4      // workgroups per batch element
#define TPB   1024   // 16 waves; 1 row per thread
#define NSTEP 199

typedef unsigned long long u64;

__device__ __forceinline__ float fsig(float x) {
  return __builtin_amdgcn_rcpf(1.0f + __builtin_amdgcn_exp2f(x * -1.4426950408889634f));
}
__device__ __forceinline__ float ftanh_(float x) {
  return fmaf(2.0f, fsig(2.0f * x), -1.0f);
}
__device__ __forceinline__ u64 packvt(float v, unsigned tag) {
  return ((u64)tag << 32) | (u64)__float_as_uint(v);
}
__device__ __forceinline__ u64 fresh_read(u64* p) {
  return __hip_atomic_fetch_add(p, 0ull, __ATOMIC_RELAXED, __HIP_MEMORY_SCOPE_AGENT);
}
__device__ __forceinline__ void fresh_write(u64* p, u64 v) {
  (void)__hip_atomic_exchange(p, v, __ATOMIC_RELAXED, __HIP_MEMORY_SCOPE_AGENT);
}

__global__ void lpkt_init(float* out) {
  int i = threadIdx.x;
  if (i < Bv) out[i * Sv] = 0.0f;
}

// Grid = 256 blocks of 1024 threads = 1 block/CU (deadlock-safe co-residency).
// amdgpu_waves_per_eu(4,4): pin allocator budget to 512/4 = 128 VGPRs —
// h[32]+acc[32]+scratch fits, killing the 64-VGPR spill pathology seen in
// R7/R10 (VGPR_Count=64, WRITE_SIZE 122-159 MB of scratch traffic).
// blockIdx = wg*64 + b  =>  XCD (blockIdx%8) = b%8: all 4 partner WGs of one
// batch element share an XCD -> post/poll atomics stay in one L2.
__global__ __launch_bounds__(TPB)
__attribute__((amdgpu_waves_per_eu(4, 4)))
void lpkt_main(
    const int* __restrict__ e_data, const int* __restrict__ at_data,
    const int* __restrict__ it_data, const float* __restrict__ a_data,
    const float* __restrict__ q_matrix,
    const float* __restrict__ E_e, const float* __restrict__ E_at, const float* __restrict__ E_it,
    const float* __restrict__ W1, const float* __restrict__ b1,
    const float* __restrict__ W2, const float* __restrict__ b2,
    const float* __restrict__ W3, const float* __restrict__ b3,
    const float* __restrict__ W4, const float* __restrict__ b4,
    const float* __restrict__ W5, const float* __restrict__ b5,
    const float* __restrict__ h0, float* __restrict__ out,
    u64* __restrict__ partial)
{
  const int tid  = threadIdx.x;
  const int b    = blockIdx.x & 63;
  const int wg   = blockIdx.x >> 6;      // 0..3
  const int lane = tid & 63;
  const int wave = tid >> 6;             // 0..15
  const int row  = wg * TPB + tid;       // 0..4095

  // transposed, +1-padded weights: lane j reads [i*33+j] conflict-free
  __shared__ float W2T[128 * 33], W3T[128 * 33];
  __shared__ float W1T[96 * 33];
  __shared__ float W4cT[64 * 33];        // W4cT[d][j] = W4[j][32+d]
  __shared__ float W4hT[32 * 33];        // W4hT[d][j] = W4[j][d]
  __shared__ float W5T[64 * 33];
  __shared__ float bs[5 * 32];
  __shared__ __align__(16) float lc_s[2][DKv];
  __shared__ __align__(16) float ht_s[DKv];
  __shared__ __align__(16) float LG_s[DKv], c_s[DKv];
  __shared__ __align__(16) float ht_part[2][DKv];
  __shared__ __align__(16) float h49[DKv];

  // ---- one-time weight staging
  for (int idx = tid; idx < 128 * 32; idx += TPB) {
    int i = idx & 127, j = idx >> 7;
    W2T[i * 33 + j] = W2[j * 128 + i];
    W3T[i * 33 + j] = W3[j * 128 + i];
  }
  for (int idx = tid; idx < 32 * 96; idx += TPB) {
    int j = idx / 96, d = idx % 96;
    W1T[d * 33 + j] = W1[idx];
    float v = W4[idx];
    if (d < 32) W4hT[d * 33 + j] = v;
    else        W4cT[(d - 32) * 33 + j] = v;
  }
  for (int idx = tid; idx < 32 * 64; idx += TPB) {
    int j = idx >> 6, i = idx & 63;
    W5T[i * 33 + j] = W5[idx];
  }
  if (tid < 32) {
    bs[tid] = b1[tid]; bs[32 + tid] = b2[tid]; bs[64 + tid] = b3[tid];
    bs[96 + tid] = b4[tid]; bs[128 + tid] = b5[tid];
    ht_part[0][tid] = 0.0f; ht_part[1][tid] = 0.0f;
    lc_s[0][tid] = 0.0f; lc_s[1][tid] = 0.0f;        // lp = 0 at t=0
  }
  if (wg == 0 && tid < DKv) h49[tid] = h0[4096 * DKv + tid];

  // ---- persistent row state (1 row/thread)
  float h[DKv];
  {
    const float4* hp = (const float4*)(h0 + (size_t)row * DKv);
#pragma unroll
    for (int i = 0; i < 8; i++) {
      float4 v = hp[i];
      h[4*i] = v.x; h[4*i+1] = v.y; h[4*i+2] = v.z; h[4*i+3] = v.w;
    }
  }
  float qc = q_matrix[(size_t)e_data[b * Sv] * NQ1v + row];
  float qc49 = 0.0f;
  if (wg == 0 && wave == 0 && lane < DKv)
    qc49 = q_matrix[(size_t)e_data[b * Sv] * NQ1v + 4096];
  __syncthreads();

  // ---- phase 0: h_tilde0 into buf[1]; post tag=1
  if (qc != 0.0f) {
#pragma unroll
    for (int kk = 0; kk < DKv; kk++) atomicAdd(&ht_part[1][kk], h[kk]);
  }
  if (wg == 0 && wave == 0 && lane < DKv && qc49 != 0.0f)
    atomicAdd(&ht_part[1][lane], h49[lane]);
  __syncthreads();
  if (wave == 0 && lane < DKv) {
    fresh_write(&partial[((size_t)(1 % 3) * Bv + b) * (NWG * DKv) + wg * DKv + lane],
                packvt(ht_part[1][lane], 1u));
    ht_part[1][lane] = 0.0f;   // next write: SEG3(t=1), after B1(1)
  }

  // =================== time loop (3 barriers/step) ===================
  for (int t = 0; t < NSTEP; t++) {
    const int par = t & 1;
    const unsigned tau_g = (unsigned)(t + 1);
    const unsigned tau_p = (unsigned)(t + 2);

    // wave-uniform scalars for this step
    const int ec  = e_data[b * Sv + t];
    const int atc = at_data[b * Sv + t];
    const int itc = it_data[b * Sv + t];
    const float av = a_data[b * Sv + t];
    const float* eerow = E_e  + (size_t)ec  * DKv;   // uniform rows -> s_loads
    const float* atrow = E_at + (size_t)atc * DKv;
    const float* itrow = E_it + (size_t)itc * DKv;

    // prefetch next q entry
    const float* qnr = q_matrix + (size_t)e_data[b * Sv + t + 1] * NQ1v;
    float qn = qnr[row];
    float qn49 = 0.0f;
    if (wg == 0 && wave == 0 && lane < DKv) qn49 = qnr[4096];

    // ---- bulk matvec: acc = W4h . h (uniform W4 -> s_load)
    float acc[DKv];
#pragma unroll
    for (int kk = 0; kk < DKv; kk++) {
      float a = 0.0f;
#pragma unroll
      for (int d = 0; d < DKv; d += 4) {
        float4 w = *(const float4*)&W4[kk * 96 + d];
        a = fmaf(w.x, h[d+0], a); a = fmaf(w.y, h[d+1], a);
        a = fmaf(w.z, h[d+2], a); a = fmaf(w.w, h[d+3], a);
      }
      acc[kk] = a;
    }

    // ---- SEG1 (wave0): poll->ht_s (lanes<32) | lc->lc_s (lanes>=32)
    if (wave == 0) {
      if (lane < 32) {
        u64* pb = partial + ((size_t)(tau_g % 3) * Bv + b) * (NWG * DKv) + lane;
        u64 v[NWG];
        for (;;) {
          bool ok = true;
#pragma unroll
          for (int w2 = 0; w2 < NWG; w2++) {
            v[w2] = fresh_read(&pb[w2 * DKv]);
            ok = ok && ((unsigned)(v[w2] >> 32) == tau_g);
          }
          if (ok) break;
          __builtin_amdgcn_s_sleep(2);
        }
        float s = 0.0f;
#pragma unroll
        for (int w2 = 0; w2 < NWG; w2++) s += __uint_as_float((unsigned)v[w2]);
        ht_s[lane] = s;
      } else {
        const int jx = lane - 32;
        float s = bs[jx];
#pragma unroll
        for (int i = 0; i < 32; i++) s = fmaf(eerow[i], W1T[i * 33 + jx], s);
#pragma unroll
        for (int i = 0; i < 32; i++) s = fmaf(atrow[i], W1T[(32 + i) * 33 + jx], s);
#pragma unroll
        for (int i = 0; i < 32; i++) s = fmaf(av,       W1T[(64 + i) * 33 + jx], s);
        lc_s[par][jx] = s;
      }
    }
    __syncthreads();   // B0: ht_s, lc_s[par] published

    // ---- SEG2: wave0: lg/gl -> LG, c | wave1 (wg0): y output for step t
    float LGreg = 0.0f, creg = 0.0f;
    if (wave == 0) {
      const int jx = lane & 31;
      float s = (lane < 32) ? bs[32 + jx] : bs[64 + jx];
      const float* WT = (lane < 32) ? W2T : W3T;
#pragma unroll
      for (int i = 0; i < 32; i++) s = fmaf(lc_s[1 - par][i], WT[i * 33 + jx], s);
#pragma unroll
      for (int i = 0; i < 32; i++) s = fmaf(itrow[i],         WT[(32 + i) * 33 + jx], s);
#pragma unroll
      for (int i = 0; i < 32; i++) s = fmaf(lc_s[par][i],     WT[(64 + i) * 33 + jx], s);
#pragma unroll
      for (int i = 0; i < 32; i++) s = fmaf(ht_s[i],          WT[(96 + i) * 33 + jx], s);
      float v = (lane < 32) ? ftanh_(s) : fsig(s);
      float pr = __shfl_xor(v, 32);
      // all 64 lanes hold LG_{jx}: lo half v=lg, pr=gl; hi half v=gl, pr=lg
      LGreg = (lane < 32) ? pr * (v + 1.0f) * 0.5f : v * (pr + 1.0f) * 0.5f;
      if (lane < 32) {
        LG_s[lane] = LGreg;
        float c = bs[96 + lane];
#pragma unroll
        for (int d = 0; d < 32; d++)
          c = fmaf(__shfl(LGreg, d), W4cT[d * 33 + lane], c);   // reg broadcast
#pragma unroll
        for (int d = 0; d < 32; d++)
          c = fmaf(itrow[d], W4cT[(32 + d) * 33 + lane], c);
        creg = c; c_s[lane] = c;
      }
    } else if (wg == 0 && wave == 1 && t >= 1 && lane < 32) {
      // y for out[t]: needs ht_s (valid post-B0) + eerow; off wave0's path
      float y = bs[128 + lane];
#pragma unroll
      for (int i = 0; i < 32; i++) y = fmaf(eerow[i], W5T[i * 33 + lane], y);
#pragma unroll
      for (int i = 0; i < 32; i++) y = fmaf(ht_s[i],  W5T[(32 + i) * 33 + lane], y);
      y = fsig(y);
#pragma unroll
      for (int m = 1; m < 32; m <<= 1) y += __shfl_xor(y, m);
      if (lane == 0) out[b * Sv + t] = y * (1.0f / DKv);
    }
    __syncthreads();   // B1: LG_s, c_s published

    // ---- SEG3 (all): row update + sparse h_tilde atomics
#pragma unroll
    for (int kk = 0; kk < DKv; kk++) {
      float g = fsig(acc[kk] + c_s[kk]);
      h[kk] = fmaf(g, h[kk], qc * LG_s[kk]);
    }
    if (qn != 0.0f) {
#pragma unroll
      for (int kk = 0; kk < DKv; kk++) atomicAdd(&ht_part[par][kk], h[kk]);
    }
    qc = qn;
    if (wg == 0 && wave == 0 && lane < DKv) {   // special row 4096 (regs for LG/c)
      float a = creg;
#pragma unroll
      for (int d = 0; d < DKv; d++) a = fmaf(W4hT[d * 33 + lane], h49[d], a);
      float hold = h49[lane];
      float hn = fmaf(fsig(a), hold, qc49 * LGreg);
      h49[lane] = hn;
      if (qn49 != 0.0f) atomicAdd(&ht_part[par][lane], hn);
      qc49 = qn49;
    }
    __syncthreads();   // B2: ht_part[par] complete (incl. special)

    // ---- post + zero (wave0); other waves race into t+1 bulk
    if (wave == 0 && lane < DKv) {
      fresh_write(&partial[((size_t)(tau_p % 3) * Bv + b) * (NWG * DKv) + wg * DKv + lane],
                  packvt(ht_part[par][lane], tau_p));
      ht_part[par][lane] = 0.0f;   // next write guarded by B1(t+2)
    }
  }

  // =================== epilogue: out[199] ===================
  if (wg == 0 && wave == 0 && lane < 32) {
    const unsigned tau_f = (unsigned)(NSTEP + 1);   // 200
    u64* pb = partial + ((size_t)(tau_f % 3) * Bv + b) * (NWG * DKv) + lane;
    u64 v[NWG];
    for (;;) {
      bool ok = true;
#pragma unroll
      for (int w2 = 0; w2 < NWG; w2++) {
        v[w2] = fresh_read(&pb[w2 * DKv]);
        ok = ok && ((unsigned)(v[w2] >> 32) == tau_f);
      }
      if (ok) break;
      __builtin_amdgcn_s_sleep(2);
    }
    float s = 0.0f;
#pragma unroll
    for (int w2 = 0; w2 < NWG; w2++) s += __uint_as_float((unsigned)v[w2]);
    ht_s[lane] = s;
  }
  __syncthreads();   // publish ht_s for the y lanes
  if (wg == 0 && wave == 0 && lane >= 32) {
    const int jx = lane - 32;
    const float* enrow = E_e + (size_t)e_data[b * Sv + NSTEP] * DKv;
    float y = bs[128 + jx];
#pragma unroll
    for (int i = 0; i < 32; i++) y = fmaf(enrow[i], W5T[i * 33 + jx], y);
#pragma unroll
    for (int i = 0; i < 32; i++) y = fmaf(ht_s[i],  W5T[(32 + i) * 33 + jx], y);
    y = fsig(y);
#pragma unroll
    for (int m = 1; m < 32; m <<= 1) y += __shfl_xor(y, m);
    if (lane == 32) out[b * Sv + NSTEP] = y * (1.0f / DKv);
  }
}

extern "C" void kernel_launch(void* const* d_in, const int* in_sizes, int n_in,
                              void* d_out, int out_size, void* d_ws, size_t ws_size,
                              hipStream_t stream) {
  const int*   e_data   = (const int*)d_in[0];
  const int*   at_data  = (const int*)d_in[1];
  const int*   it_data  = (const int*)d_in[2];
  const float* a_data   = (const float*)d_in[3];
  const float* q_matrix = (const float*)d_in[4];
  const float* E_e      = (const float*)d_in[5];
  const float* E_at     = (const float*)d_in[6];
  const float* E_it     = (const float*)d_in[7];
  const float* W1 = (const float*)d_in[8];
  const float* b1 = (const float*)d_in[9];
  const float* W2 = (const float*)d_in[10];
  const float* b2 = (const float*)d_in[11];
  const float* W3 = (const float*)d_in[12];
  const float* b3 = (const float*)d_in[13];
  const float* W4 = (const float*)d_in[14];
  const float* b4 = (const float*)d_in[15];
  const float* W5 = (const float*)d_in[16];
  const float* b5 = (const float*)d_in[17];
  const float* h0 = (const float*)d_in[18];
  float* out = (float*)d_out;

  u64* partial = (u64*)d_ws;   // [3][Bv][NWG][DKv] tagged (tag<<32|value) words

  lpkt_init<<<1, 64, 0, stream>>>(out);
  lpkt_main<<<dim3(Bv * NWG), dim3(TPB), 0, stream>>>(
      e_data, at_data, it_data, a_data, q_matrix, E_e, E_at, E_it,
      W1, b1, W2, b2, W3, b3, W4, b4, W5, b5, h0, out, partial);
}